// Round 6
// baseline (220.638 us; speedup 1.0000x reference)
//
#include <hip/hip_runtime.h>
#include <hip/hip_bf16.h>

// Problem constants
#define NB 256
#define NACT 21
#define NA 8192
#define NE 262144
#define CSR_CAP 128
#define LOG2E 1.44269504f

#if __has_builtin(__builtin_amdgcn_exp2f)
#define EXP2F(x) __builtin_amdgcn_exp2f(x)
#else
#define EXP2F(x) exp2f(x)
#endif

typedef __attribute__((ext_vector_type(8))) short short8;
typedef __attribute__((ext_vector_type(4))) float float4v;

__device__ inline float wsum64(float v) {
#pragma unroll
  for (int m = 32; m > 0; m >>= 1) v += __shfl_xor(v, m, 64);
  return v;
}

__device__ inline unsigned short f2bf(float f) {
  union { __hip_bfloat16 h; unsigned short u; } cv;
  cv.h = __float2bfloat16(f);
  return cv.u;
}

__device__ inline float bf2f(unsigned short u) {
  union { unsigned int u; float f; } cv;
  cv.u = ((unsigned int)u) << 16;
  return cv.f;
}

// ---------------- k_ic: conv1+im2col (blocks 0..255) | cnt zero (256..271) | c2w->bf16 (272..307) ----------------
__global__ __launch_bounds__(512, 2) void k_ic(
    const float* __restrict__ x, const float* __restrict__ c1w, const float* __restrict__ c1b_,
    const float* __restrict__ c2w, unsigned short* c1b, unsigned short* w2abf, int* cnt) {
  __shared__ float sm[3437];  // xs[845] w1s[1440] c1s[1152]
  int t = threadIdx.x, b = blockIdx.x;
  if (b >= 272) {  // c2w -> bf16 (64*288 = 18432 values)
    int i = (b - 272) * 512 + t;
    w2abf[i] = f2bf(c2w[i]);
    return;
  }
  if (b >= 256) {  // zero cnt
    cnt[(b - 256) * 512 + t] = 0;
    return;
  }
  // conv1 for image b + im2col write
  float* xs = sm;
  float* w1s = sm + 845;
  float* c1s = sm + 2285;
  for (int i = t; i < 845; i += 512) xs[i] = x[b * 845 + i];
  for (int i = t; i < 1440; i += 512) w1s[i] = c1w[i];
  __syncthreads();
  for (int idx = t; idx < 1152; idx += 512) {
    int oc = idx / 36, p = idx - oc * 36;
    int oy = p / 6, ox = p - oy * 6;
    float acc = c1b_[oc];
    const float* wp = &w1s[oc * 45];
#pragma unroll
    for (int ic = 0; ic < 5; ic++)
#pragma unroll
      for (int ky = 0; ky < 3; ky++)
#pragma unroll
        for (int kx = 0; kx < 3; kx++)
          acc += xs[ic * 169 + (oy * 2 + ky) * 13 + ox * 2 + kx] * wp[ic * 9 + ky * 3 + kx];
    c1s[idx] = fmaxf(acc, 0.0f);
  }
  __syncthreads();
  // im2col: c1b[(b*16+p)*288 + k]
  for (int i = t; i < 4608; i += 512) {
    int p = i / 288, k = i - p * 288;
    int ic = k / 9, r = k - ic * 9;
    int ky = r / 3, kx = r - ky * 3;
    int oy = p >> 2, ox = p & 3;
    c1b[b * 4608 + i] = f2bf(c1s[ic * 36 + (oy + ky) * 6 + ox + kx]);
  }
}

// ---------------- k_pc: prep (blocks 0..511) + conv2 GEMM via MFMA (blocks 512..527) ----------------
__global__ __launch_bounds__(512, 2) void k_pc(
    const int* __restrict__ edges, const float* __restrict__ fcw,
    const float* __restrict__ g2w, const float* __restrict__ g2b,
    unsigned short* fcwbf, unsigned short* w2t, float* wpart, int* cnt, int* csr,
    const unsigned short* __restrict__ c1b, const unsigned short* __restrict__ w2abf,
    const float* __restrict__ c2b, unsigned short* h1024bf) {
  __shared__ float sm[288];  // prep: red[16][17] + b2s[16]
  int t = threadIdx.x;
  int wave = t >> 6, lane = t & 63;
  if (blockIdx.x < 512) {  // ---- prep ----
    float (*red)[17] = (float(*)[17])sm;
    float* b2s = sm + 272;
    int blk = blockIdx.x;
    {  // CSR: 1 edge per thread
      int e = blk * 512 + t;
      int s = edges[2 * e], d = edges[2 * e + 1];
      int slot = atomicAdd(&cnt[d], 1);
      if (slot < CSR_CAP) csr[d * CSR_CAP + slot] = s;
    }
    {  // fcw -> bf16
      int base = (blk * 512 + t) * 2;
      float2 v = *(const float2*)&fcw[base];
      fcwbf[base + 0] = f2bf(v.x);
      fcwbf[base + 1] = f2bf(v.y);
    }
    {  // W2 transpose + partials
      if (t < 256) {
        int jj = t >> 4, k = t & 15;
        int j = blk * 16 + jj;
        float w = g2w[k * 8192 + j];
        w2t[j * 16 + k] = f2bf(w);
        red[jj][k] = w;
      }
      if (t < 16) b2s[t] = g2b[blk * 16 + t];
      __syncthreads();
      if (t < 16) {
        float s = 0.0f;
#pragma unroll
        for (int q = 0; q < 16; q++) s += red[q][t];
        wpart[blk * 17 + t] = s;
      } else if (t == 16) {
        float s = 0.0f;
#pragma unroll
        for (int q = 0; q < 16; q++) s += b2s[q];
        wpart[blk * 17 + 16] = s;
      }
    }
  } else {  // ---- conv2 GEMM ----
    int nb = blockIdx.x - 512;          // 0..15
    int nbase = nb * 256 + wave * 32;
    int m = lane & 15, quad = lane >> 4;
    float4v z = {0.0f, 0.0f, 0.0f, 0.0f};
    float4v acc00 = z, acc01 = z, acc02 = z, acc03 = z;
    float4v acc10 = z, acc11 = z, acc12 = z, acc13 = z;
#pragma unroll
    for (int ks = 0; ks < 9; ks++) {
      int ko = ks * 32 + quad * 8;
      short8 a0 = *(const short8*)&w2abf[(0 * 16 + m) * 288 + ko];
      short8 a1 = *(const short8*)&w2abf[(1 * 16 + m) * 288 + ko];
      short8 a2 = *(const short8*)&w2abf[(2 * 16 + m) * 288 + ko];
      short8 a3 = *(const short8*)&w2abf[(3 * 16 + m) * 288 + ko];
      short8 b0 = *(const short8*)&c1b[(nbase + m) * 288 + ko];
      short8 b1 = *(const short8*)&c1b[(nbase + 16 + m) * 288 + ko];
      acc00 = __builtin_amdgcn_mfma_f32_16x16x32_bf16(a0, b0, acc00, 0, 0, 0);
      acc01 = __builtin_amdgcn_mfma_f32_16x16x32_bf16(a1, b0, acc01, 0, 0, 0);
      acc02 = __builtin_amdgcn_mfma_f32_16x16x32_bf16(a2, b0, acc02, 0, 0, 0);
      acc03 = __builtin_amdgcn_mfma_f32_16x16x32_bf16(a3, b0, acc03, 0, 0, 0);
      acc10 = __builtin_amdgcn_mfma_f32_16x16x32_bf16(a0, b1, acc10, 0, 0, 0);
      acc11 = __builtin_amdgcn_mfma_f32_16x16x32_bf16(a1, b1, acc11, 0, 0, 0);
      acc12 = __builtin_amdgcn_mfma_f32_16x16x32_bf16(a2, b1, acc12, 0, 0, 0);
      acc13 = __builtin_amdgcn_mfma_f32_16x16x32_bf16(a3, b1, acc13, 0, 0, 0);
    }
    float4v accs[2][4] = {{acc00, acc01, acc02, acc03}, {acc10, acc11, acc12, acc13}};
#pragma unroll
    for (int nt = 0; nt < 2; nt++) {
#pragma unroll
      for (int mt = 0; mt < 4; mt++) {
#pragma unroll
        for (int r = 0; r < 4; r++) {
          int oc = mt * 16 + quad * 4 + r;
          int n = nbase + nt * 16 + m;
          int img = n >> 4, pos = n & 15;
          h1024bf[img * 1024 + oc * 16 + pos] =
              f2bf(fmaxf(accs[nt][mt][r] + c2b[oc], 0.0f));
        }
      }
    }
  }
}

// ---------------- k_fhe: head (0..15) | enc (16..79) | dinv/xs2 (80..95) | wsf (96) ----------------
// FC GEMM computed inside consumer blocks (hidden never materialized in HBM).
__global__ __launch_bounds__(512, 2) void k_fhe(
    const int* __restrict__ cnt, const float* __restrict__ x_msg,
    const unsigned short* __restrict__ h1024bf, const unsigned short* __restrict__ fcwbf,
    const float* __restrict__ fcb, const float* __restrict__ muw, const float* __restrict__ mub,
    const float* __restrict__ msgw, const float* __restrict__ msgb,
    const int* __restrict__ action, const float* __restrict__ wpart,
    float* es2, float* dinv, float* xs2, float* wsf, float* out) {
  __shared__ __align__(16) unsigned short hidbf[8192];  // hidden[16][512] bf16
  __shared__ float smf[512];                            // logits / wsf partials
  int t = threadIdx.x, b = blockIdx.x;
  int wave = t >> 6, lane = t & 63;
  if (b >= 96) {  // wsf reduce (once)
    if (t < 272) {
      int q = t / 17, c = t - q * 17;
      float s = 0.0f;
      for (int r = q; r < 512; r += 16) s += wpart[r * 17 + c];
      smf[t] = s;
    }
    __syncthreads();
    if (t < 17) {
      float s = 0.0f;
#pragma unroll
      for (int q = 0; q < 16; q++) s += smf[q * 17 + t];
      wsf[t] = s;
    }
    return;
  }
  if (b >= 80) {  // dinv/xs2
    int i = (b - 80) * 512 + t;
    float d = rsqrtf((float)cnt[i] + 1.0f);
    dinv[i] = d;
    xs2[i] = d * x_msg[i];
    return;
  }
  // ---- phase 1: hidden[16][512] via MFMA (head: rows b*16..; enc: rows 0..15, row 0 used) ----
  int r0 = (b < 16) ? b * 16 : 0;
  int m = lane & 15, quad = lane >> 4;
  {
    const unsigned short* ap = &h1024bf[(r0 + m) * 1024 + quad * 8];
#pragma unroll
    for (int tc = 0; tc < 4; tc++) {
      int col0 = wave * 64 + tc * 16;
      const unsigned short* bp = &fcwbf[(col0 + m) * 1024 + quad * 8];
      float4v acc = {0.0f, 0.0f, 0.0f, 0.0f};
#pragma unroll
      for (int ks = 0; ks < 32; ks++) {
        short8 av = *(const short8*)(ap + ks * 32);
        short8 bv = *(const short8*)(bp + ks * 32);
        acc = __builtin_amdgcn_mfma_f32_16x16x32_bf16(av, bv, acc, 0, 0, 0);
      }
#pragma unroll
      for (int r = 0; r < 4; r++) {
        int i = quad * 4 + r;  // batch-row-local (D row)
        hidbf[i * 512 + col0 + m] = f2bf(fmaxf(acc[r] + fcb[col0 + m], 0.0f));
      }
    }
  }
  __syncthreads();
  if (b < 16) {  // ---- head: logits via MFMA, then softmax ----
    if (wave < 2) {  // wave = action col-tile (cols 0..15 / 16..31)
      int col0 = wave * 16;
      int act_i = col0 + m;
      float bias = (act_i < NACT) ? mub[act_i] : 0.0f;
      float4v acc = {bias, bias, bias, bias};
#pragma unroll
      for (int ks = 0; ks < 16; ks++) {  // K = 512
        short8 av = *(const short8*)&hidbf[m * 512 + ks * 32 + quad * 8];
        short8 bv = {0, 0, 0, 0, 0, 0, 0, 0};
        if (act_i < NACT) {
          const float* wp = &muw[act_i * 512 + ks * 32 + quad * 8];
#pragma unroll
          for (int q2 = 0; q2 < 8; q2++) bv[q2] = (short)f2bf(wp[q2]);
        }
        acc = __builtin_amdgcn_mfma_f32_16x16x32_bf16(av, bv, acc, 0, 0, 0);
      }
#pragma unroll
      for (int r = 0; r < 4; r++) smf[(quad * 4 + r) * 32 + col0 + m] = acc[r];
    }
    __syncthreads();
#pragma unroll
    for (int rr = 0; rr < 2; rr++) {
      int rloc = wave * 2 + rr;
      int bb = r0 + rloc;
      float logit = (lane < NACT) ? smf[rloc * 32 + lane] : -1e30f;
      float mx = logit;
#pragma unroll
      for (int s = 32; s > 0; s >>= 1) mx = fmaxf(mx, __shfl_xor(mx, s, 64));
      float e = (lane < NACT) ? __expf(logit - mx) : 0.0f;
      float se = wsum64(e);
      float swl = wsum64(e * logit);
      float lse = mx + __logf(se);
      int act = action[bb];
      if (lane == 0) {
        out[bb] = (float)act;                  // action passthrough
        out[8704 + bb] = lse - swl / se;       // entropy
      }
      if (lane == act) out[8448 + bb] = logit - lse;  // log_prob
    }
  } else {  // ---- enc: es2[j] = dinv[j] * (msgw[j].hidden0 + msgb[j]), 128 rows/block ----
    float h0[8];
#pragma unroll
    for (int q2 = 0; q2 < 8; q2++) h0[q2] = bf2f(hidbf[lane * 8 + q2]);
    int jbase = (b - 16) * 128 + wave * 16;
    for (int j = jbase; j < jbase + 16; j++) {
      const float* wp = &msgw[j * 512 + lane * 8];
      float4 w0 = *(const float4*)(wp);
      float4 w1 = *(const float4*)(wp + 4);
      float s = w0.x * h0[0] + w0.y * h0[1] + w0.z * h0[2] + w0.w * h0[3] +
                w1.x * h0[4] + w1.y * h0[5] + w1.z * h0[6] + w1.w * h0[7];
      s = wsum64(s);
      if (lane == 0) es2[j] = rsqrtf((float)cnt[j] + 1.0f) * (s + msgb[j]);
    }
  }
}

// ---------------- k_g1: GCN1 gather (2 rows per wave, 512 blocks) ----------------
__global__ __launch_bounds__(512, 4) void k_g1(
    const int* __restrict__ cnt, const int* __restrict__ csr,
    const float* __restrict__ dinv, const float* __restrict__ xs2,
    const float* __restrict__ es2, const float* __restrict__ g1w,
    const float* __restrict__ g1b, float* gbuf2) {
  int t = threadIdx.x, blk = blockIdx.x;
  int wave = t >> 6, lane = t & 63;
  int wg = blk * 8 + wave;  // 0..4095
#pragma unroll
  for (int rr = 0; rr < 2; rr++) {
    int i = wg * 2 + rr;
    int ci = min(cnt[i], CSR_CAP);
    float di = dinv[i];
    float a0 = 0.0f, a1 = 0.0f;
    for (int e = lane; e < ci; e += 64) {
      int s = csr[i * CSR_CAP + e];
      a0 += xs2[s];
      a1 += es2[s];
    }
    float f0 = (wsum64(a0) + xs2[i]) * di;
    float f1 = (wsum64(a1) + es2[i]) * di;
    if (lane < 16) {
      float gv = fmaxf(f0 * g1w[lane] + f1 * g1w[16 + lane] + g1b[lane], 0.0f);
      gbuf2[i * 16 + lane] = di * gv;
    }
  }
}

// ---------------- k_msg: GCN2 gather + MFMA scores + sum-exp (16 rows/block, 512 blocks) ----------------
__global__ __launch_bounds__(512, 2) void k_msg(
    const int* __restrict__ cnt, const int* __restrict__ csr,
    const float* __restrict__ dinv, const float* __restrict__ gbuf2,
    const float* __restrict__ wsf, const unsigned short* __restrict__ w2t,
    const float* __restrict__ g2b, float* out) {
  __shared__ __align__(16) unsigned short vbf[256];
  __shared__ float vf[256];
  __shared__ float pl[2048];
  __shared__ float sl[128];
  __shared__ float wsfs[17];
  int t = threadIdx.x, blk = blockIdx.x;
  int wave = t >> 6, lane = t & 63;
  int rowbase = blk * 16;
  if (t < 17) wsfs[t] = wsf[t];
  {  // gather 16 V rows
    int eq = lane >> 4, c = lane & 15;
#pragma unroll
    for (int rr = 0; rr < 2; rr++) {
      int il = wave * 2 + rr;
      int i = rowbase + il;
      int ci = min(cnt[i], CSR_CAP);
      float di = dinv[i];
      float acc = (eq == 0) ? gbuf2[i * 16 + c] : 0.0f;
      for (int e = eq; e < ci; e += 4) {
        int s = csr[i * CSR_CAP + e];
        acc += gbuf2[s * 16 + c];
      }
      acc *= di;
      acc += __shfl_xor(acc, 16, 64);
      acc += __shfl_xor(acc, 32, 64);
      if (eq == 0) {
        vf[il * 16 + c] = acc;
        vbf[il * 16 + c] = f2bf(acc * LOG2E);
      }
    }
  }
  __syncthreads();
  float myMean = 0.0f;
  if (t < 16) {
    float dot = 0.0f;
#pragma unroll
    for (int c = 0; c < 16; c++) dot += vf[t * 16 + c] * wsfs[c];
    myMean = (dot + wsfs[16]) * (1.0f / 8192.0f);
  }
  {  // scores via MFMA + exp2
    int quad = lane >> 4, n = lane & 15;
    int k8 = quad * 8;
    short8 za = {0, 0, 0, 0, 0, 0, 0, 0};
    short8 a1 = za;
    if (quad < 2) a1 = *(const short8*)&vbf[n * 16 + k8];
    float sacc[4];
#pragma unroll
    for (int q = 0; q < 4; q++) sacc[q] = 0.0f;
    int colb = wave * 1024 + n;
    for (int tp = 0; tp < 64; tp += 2) {
      int col1 = colb + tp * 16;
      int col2 = col1 + 16;
      short8 b1 = za, b2 = za;
      if (quad < 2) {
        b1 = *(const short8*)&w2t[col1 * 16 + k8];
        b2 = *(const short8*)&w2t[col2 * 16 + k8];
      }
      float bb1 = g2b[col1] * LOG2E, bb2 = g2b[col2] * LOG2E;
      float4v c1 = {bb1, bb1, bb1, bb1};
      float4v c2 = {bb2, bb2, bb2, bb2};
      float4v s11 = __builtin_amdgcn_mfma_f32_16x16x32_bf16(a1, b1, c1, 0, 0, 0);
      float4v s12 = __builtin_amdgcn_mfma_f32_16x16x32_bf16(a1, b2, c2, 0, 0, 0);
#pragma unroll
      for (int r = 0; r < 4; r++) sacc[r] += EXP2F(s11[r]) + EXP2F(s12[r]);
    }
#pragma unroll
    for (int q = 0; q < 4; q++) {
      int rl = quad * 4 + q;
      pl[rl * 128 + wave * 16 + n] = sacc[q];
    }
  }
  __syncthreads();
  if (t < 128) {
    int r = t >> 3, seg = t & 7;
    int base = r * 128 + seg * 16;
    float ll = 0.0f;
#pragma unroll
    for (int i = 0; i < 16; i++) ll += pl[base + i];
    sl[r * 8 + seg] = ll;
  }
  __syncthreads();
  if (t < 16) {
    float ll = 0.0f;
#pragma unroll
    for (int i = 0; i < 8; i++) ll += sl[t * 8 + i];
    out[256 + rowbase + t] = myMean - __logf(ll);
  }
}

extern "C" void kernel_launch(void* const* d_in, const int* in_sizes, int n_in,
                              void* d_out, int out_size, void* d_ws, size_t ws_size,
                              hipStream_t stream) {
  const float* x     = (const float*)d_in[0];
  const float* x_msg = (const float*)d_in[1];
  const int*   edges = (const int*)d_in[2];
  const int*   action= (const int*)d_in[3];
  const float* c1w   = (const float*)d_in[4];
  const float* c1bb  = (const float*)d_in[5];
  const float* c2w   = (const float*)d_in[6];
  const float* c2b   = (const float*)d_in[7];
  const float* fcw   = (const float*)d_in[8];
  const float* fcb   = (const float*)d_in[9];
  const float* muw   = (const float*)d_in[10];
  const float* mub   = (const float*)d_in[11];
  const float* msgw  = (const float*)d_in[12];
  const float* msgb  = (const float*)d_in[13];
  const float* g1w   = (const float*)d_in[14];
  const float* g1b   = (const float*)d_in[15];
  const float* g2w   = (const float*)d_in[16];
  const float* g2b   = (const float*)d_in[17];
  float* out = (float*)d_out;  // reference outputs are fp32

  float* ws     = (float*)d_ws;
  unsigned short* h1024bf = (unsigned short*)ws;            // 262144 bf16 = 131072 f
  unsigned short* fcwbf   = (unsigned short*)(ws + 131072); // 524288 bf16 = 262144 f
  float* es2    = ws + 524288;           // 8192
  float* dinv   = ws + 532480;           // 8192
  float* xs2    = ws + 540672;           // 8192
  float* gbuf2  = ws + 548864;           // 131072
  float* wpart  = ws + 679936;           // 8704
  unsigned short* w2t = (unsigned short*)(ws + 688640);     // 131072 bf16 = 65536 f
  int*   cnt    = (int*)(ws + 754176);   // 8192 ints
  int*   csr    = (int*)(ws + 762368);   // 1048576 ints -> ends at float-offset 1810944
  float* wsf    = ws + 1810944;          // 17
  unsigned short* c1b   = (unsigned short*)(ws + 1810964);  // 4096*288 bf16 = 589824 f
  unsigned short* w2abf = (unsigned short*)(ws + 2400788);  // 64*288 bf16 = 9216 f

  k_ic <<<308, 512, 0, stream>>>(x, c1w, c1bb, c2w, c1b, w2abf, cnt);
  k_pc <<<528, 512, 0, stream>>>(edges, fcw, g2w, g2b, fcwbf, w2t, wpart, cnt, csr,
                                 c1b, w2abf, c2b, h1024bf);
  k_fhe<<<97, 512, 0, stream>>>(cnt, x_msg, h1024bf, fcwbf, fcb, muw, mub, msgw, msgb,
                                action, wpart, es2, dinv, xs2, wsf, out);
  k_g1 <<<512, 512, 0, stream>>>(cnt, csr, dinv, xs2, es2, g1w, g1b, gbuf2);
  k_msg<<<512, 512, 0, stream>>>(cnt, csr, dinv, gbuf2, wsf, w2t, g2b, out);
}